// Round 20
// baseline (1840.102 us; speedup 1.0000x reference)
//
#include <hip/hip_runtime.h>
#include <hip/hip_fp16.h>

// NO-SYNC LSTM classifier, W-stream PIPELINED (round 20).
// R19 validated: zero cross-wg exchange (WRITE 32KB), correct. But 23.6us/
// step vs a ~9.6us TA floor (1444 x 1KB W wave-loads/CU/step @ ~64B/cy).
// R20 closes the overlap gap, same structure:
//  - 2-bank static W prefetch (Wb0/Wb1, 12 frags each): consume kt while
//    loading kt+2; banks for kt0/kt1 warm-load BEFORE the step barrier
//    (W is step-invariant) so loads fly during the barrier.
//  - stage_x issued BEFORE the gate VALU (embed LLC latency hides there).
//  - one intra-wg __syncthreads per step; no flags, no fences, no atomics.
// Geometry: 128 wgs x 32 rows, 512 thr (8 waves); A=[x|h] ping-pong in LDS
// (MFMA frag layout, 80KB -> 1 wg/CU); W frag-blocked in d_ws (1.52MB,
// L2-resident per XCD), streamed global->VGPR. Wave w owns jh-tiles
// {w, w+8} (+{16+w} if w<3) x 4 gates.

#define TT 22
#define STEPS 22
#define NROW 32
#define NWGD 128
#define NTHR 512                 // 8 waves, 2/SIMD
#define NKT 19                   // K = 608 (x 300 | h 300 | pad 8)
#define ASTRIDE 20480            // halves per A buffer (19456 used, padded)

typedef _Float16 f16;
typedef _Float16 f16x4 __attribute__((ext_vector_type(4)));
typedef _Float16 f16x8 __attribute__((ext_vector_type(8)));
typedef float    f32x4 __attribute__((ext_vector_type(4)));

__device__ __forceinline__ float sigm(float x) { return 1.0f / (1.0f + __expf(-x)); }
__device__ __forceinline__ float tanh_f(float x) {
    float ax = fabsf(x);
    float e = __expf(-2.0f * ax);
    return copysignf((1.0f - e) / (1.0f + e), x);
}

// Wc fragment f = (g*20 + tw)*19 + kt : 1KB block, lane l holds
// col = tw*16 + (l&15) of gate g, k = kt*32 + (l>>4)*8 .. +8.
__global__ void prep_w(const float* __restrict__ Wih, const float* __restrict__ Whh,
                       f16* __restrict__ Wc) {
    int f = blockIdx.x;             // 0..1519
    int n = f / NKT, kt = f - n * NKT;
    int g = n / 20, tw = n - g * 20;
    int l = threadIdx.x;            // 0..63
    int jh = tw * 16 + (l & 15);
    int kb = kt * 32 + (l >> 4) * 8;
    f16x8 v;
    #pragma unroll
    for (int i = 0; i < 8; ++i) {
        int k = kb + i;
        float x = 0.f;
        if (jh < 300) {
            if (k < 300)      x = Wih[(size_t)(g * 300 + jh) * 300 + k];
            else if (k < 600) x = Whh[(size_t)(g * 300 + jh) * 300 + (k - 300)];
        }
        v[i] = (f16)x;
    }
    *(f16x8*)&Wc[(size_t)f * 512 + l * 8] = v;
}

__global__ __launch_bounds__(NTHR, 2)
void lstm_ns(const int* __restrict__ cap, const int* __restrict__ cap_len,
             const float* __restrict__ embed,
             const float* __restrict__ bih, const float* __restrict__ bhh,
             const float* __restrict__ v_wn, const float* __restrict__ g_wn,
             const float* __restrict__ b_cls,
             const f16* __restrict__ Wc, float* __restrict__ out)
{
    __shared__ f16 A[2][ASTRIDE];   // 81.9KB: ping-pong [x|h] frag layout
    __shared__ int capS[NROW][TT];
    __shared__ float scaleS[2];

    const int tid = threadIdx.x;
    const int wg  = blockIdx.x;
    const int row0 = wg * NROW;
    const int wv = tid >> 6, ln = tid & 63, c = ln & 15, kg = ln >> 4;
    const int afrag = c * 32 + kg * 8;   // A-frag: row=lane&15, k-quad=lane>>4

    // ---- setup: tokens, head scale, zero BOTH A buffers ----
    for (int u = tid; u < NROW * TT; u += NTHR) {
        int rl = u / TT, t = u - rl * TT;
        capS[rl][t] = cap[(size_t)(row0 + rl) * TT + t];
    }
    if (tid < 2) {
        float s = 0.f;
        for (int k = 0; k < 300; ++k) { float v = v_wn[tid * 300 + k]; s += v * v; }
        scaleS[tid] = g_wn[tid] * rsqrtf(s);
    }
    {
        f16* Af = &A[0][0];
        for (int u = tid; u < 2 * ASTRIDE / 8; u += NTHR)
            *(f16x8*)&Af[u * 8] = (f16x8){0, 0, 0, 0, 0, 0, 0, 0};
    }
    __syncthreads();                // capS/zero visible BEFORE stage_x reads

    // ---- x staging into frag layout (chunks 0..36 full, 37 partial) ----
    auto stage_x = [&](int t, f16* An) {
        for (int u = tid; u < NROW * 38; u += NTHR) {
            int rl = u / 38, ch = u - rl * 38;
            const float* er = embed + (size_t)capS[rl][t] * 300;
            int k0 = ch * 8;
            size_t off = ((size_t)((rl >> 4) * NKT + (k0 >> 5))) * 512
                         + (rl & 15) * 32 + ((k0 >> 3) & 3) * 8;
            if (ch < 37) {
                float4 a = *(const float4*)(er + k0);
                float4 b = *(const float4*)(er + k0 + 4);
                f16x8 v;
                v[0] = (f16)a.x; v[1] = (f16)a.y; v[2] = (f16)a.z; v[3] = (f16)a.w;
                v[4] = (f16)b.x; v[5] = (f16)b.y; v[6] = (f16)b.z; v[7] = (f16)b.w;
                *(f16x8*)(An + off) = v;
            } else {                                 // k 296..299 only
                float4 a = *(const float4*)(er + 296);
                f16x4 v;
                v[0] = (f16)a.x; v[1] = (f16)a.y; v[2] = (f16)a.z; v[3] = (f16)a.w;
                *(f16x4*)(An + off) = v;
            }
        }
    };

    // ---- per-wave tile assignment (jh-tiles 0..18 live; 19 = pad) ----
    int twl[3];
    twl[0] = wv; twl[1] = wv + 8; twl[2] = 16 + wv;
    bool live[3];
    live[0] = true; live[1] = true; live[2] = (wv < 3);

    int jh[3];
    float bias[3][4];
    int hadr[3];                                    // h write base (k=300+jh)
    int wcb[3][4];                                  // Wc frag base (halves)
    #pragma unroll
    for (int tl = 0; tl < 3; ++tl) {
        int j = twl[tl] * 16 + c;
        jh[tl] = j;
        int hk = 300 + (j < 300 ? j : 299);
        hadr[tl] = (hk >> 5) * 512 + ((hk >> 3) & 3) * 8 + (hk & 7);
        #pragma unroll
        for (int g = 0; g < 4; ++g) {
            float bv = 0.f;
            if (live[tl] && j < 300) { int jj = g * 300 + j; bv = bih[jj] + bhh[jj]; }
            bias[tl][g] = bv;
            wcb[tl][g] = ((g * 20 + twl[tl]) * NKT) * 512 + ln * 8;
        }
    }
    int lenr[2][4];
    #pragma unroll
    for (int m = 0; m < 2; ++m) {
        int rb = row0 + m * 16 + kg * 4;
        #pragma unroll
        for (int rg = 0; rg < 4; ++rg) lenr[m][rg] = cap_len[rb + rg];
    }

    float cst[2][3][4] = {};
    float hreg[2][3][4] = {};
    f32x4 acc[2][3][4];

    // ---- W stream pipeline: 2 static banks, prefetch kt+2 ----
    f16x8 Wb0[3][4], Wb1[3][4];
    auto LOADW = [&](f16x8 (&Wb)[3][4], int kt) {
        #pragma unroll
        for (int tl = 0; tl < 3; ++tl) {
            if (!live[tl]) continue;
            #pragma unroll
            for (int g = 0; g < 4; ++g)
                Wb[tl][g] = *(const f16x8*)&Wc[(size_t)wcb[tl][g] + kt * 512];
        }
    };
    auto CONS = [&](f16x8 (&Wb)[3][4], const f16* Ab, int kt) {
        f16x8 a0 = *(const f16x8*)&Ab[(0 * NKT + kt) * 512 + afrag];
        f16x8 a1 = *(const f16x8*)&Ab[(1 * NKT + kt) * 512 + afrag];
        #pragma unroll
        for (int tl = 0; tl < 3; ++tl) {
            if (!live[tl]) continue;
            #pragma unroll
            for (int g = 0; g < 4; ++g) {
                acc[0][tl][g] = __builtin_amdgcn_mfma_f32_16x16x32_f16(a0, Wb[tl][g], acc[0][tl][g], 0, 0, 0);
                acc[1][tl][g] = __builtin_amdgcn_mfma_f32_16x16x32_f16(a1, Wb[tl][g], acc[1][tl][g], 0, 0, 0);
            }
        }
    };

    stage_x(0, A[0]);
    LOADW(Wb0, 0); LOADW(Wb1, 1);   // warm banks; loads fly across barrier
    __syncthreads();

    #pragma unroll 1
    for (int t = 0; t < STEPS; ++t) {
        const f16* Ab = A[t & 1];
        f16*       An = A[(t + 1) & 1];

        #pragma unroll
        for (int m = 0; m < 2; ++m)
            #pragma unroll
            for (int tl = 0; tl < 3; ++tl)
                #pragma unroll
                for (int g = 0; g < 4; ++g) {
                    float bv = bias[tl][g];
                    f32x4 b4 = {bv, bv, bv, bv};
                    acc[m][tl][g] = b4;
                }

        // K loop: consume bank / prefetch kt+2 (all static indexing)
        #pragma unroll
        for (int p = 0; p < 9; ++p) {
            CONS(Wb0, Ab, 2 * p);     LOADW(Wb0, 2 * p + 2);
            CONS(Wb1, Ab, 2 * p + 1); if (p < 8) LOADW(Wb1, 2 * p + 3);
        }
        CONS(Wb0, Ab, 18);

        // x(t+1) staging issued first: embed LLC latency hides under gates
        if (t + 1 < STEPS) stage_x(t + 1, An);

        // gates (i/f/g/o same-lane acc regs) + h(t+1) into An's h region
        #pragma unroll
        for (int m = 0; m < 2; ++m)
            #pragma unroll
            for (int tl = 0; tl < 3; ++tl) {
                if (!live[tl] || jh[tl] >= 300) continue;
                #pragma unroll
                for (int rg = 0; rg < 4; ++rg) {
                    bool upd = (t < lenr[m][rg]);
                    float iv = sigm(acc[m][tl][0][rg]);
                    float fv = sigm(acc[m][tl][1][rg]);
                    float gv = tanh_f(acc[m][tl][2][rg]);
                    float ov = sigm(acc[m][tl][3][rg]);
                    float cn = fv * cst[m][tl][rg] + iv * gv;
                    cn = upd ? cn : cst[m][tl][rg];
                    cst[m][tl][rg] = cn;
                    float hn = ov * tanh_f(cn);
                    hreg[m][tl][rg] = upd ? hn : hreg[m][tl][rg];
                    An[(size_t)(m * NKT) * 512 + hadr[tl]
                       + (size_t)(kg * 4 + rg) * 32] = (f16)hreg[m][tl][rg];
                }
            }

        LOADW(Wb0, 0); LOADW(Wb1, 1);   // warm next step across the barrier
        __syncthreads();    // intra-CU only: h/x visible, Ab free for rewrite
    }

    // ---- head: h(22) lives in A[STEPS&1] = A[0] ----
    const f16* hb = A[STEPS & 1];
    for (int u = tid; u < NROW * 2; u += NTHR) {
        int rl = u >> 1, cls = u & 1;
        float sc = scaleS[cls];
        const float* vr = v_wn + cls * 300;
        float s = 0.f;
        #pragma unroll 4
        for (int k = 0; k < 300; ++k) {
            int hk = 300 + k;
            size_t off = ((size_t)((rl >> 4) * NKT + (hk >> 5))) * 512
                         + (rl & 15) * 32 + ((hk >> 3) & 3) * 8 + (hk & 7);
            s += vr[k] * (float)hb[off];
        }
        out[(size_t)(row0 + rl) * 2 + cls] = sc * s + b_cls[cls];
    }
}

extern "C" void kernel_launch(void* const* d_in, const int* in_sizes, int n_in,
                              void* d_out, int out_size, void* d_ws, size_t ws_size,
                              hipStream_t stream) {
    const int*   cap     = (const int*)  d_in[0];
    const int*   cap_len = (const int*)  d_in[1];
    const float* embed   = (const float*)d_in[2];
    const float* W_ih    = (const float*)d_in[3];
    const float* W_hh    = (const float*)d_in[4];
    const float* b_ih    = (const float*)d_in[5];
    const float* b_hh    = (const float*)d_in[6];
    const float* v_wn    = (const float*)d_in[7];
    const float* g_wn    = (const float*)d_in[8];
    const float* b_cls   = (const float*)d_in[9];
    float* out = (float*)d_out;

    f16* Wc = (f16*)d_ws;            // 1520 frags x 1KB = 1.52 MB

    prep_w<<<1520, 64, 0, stream>>>(W_ih, W_hh, Wc);
    lstm_ns<<<NWGD, NTHR, 0, stream>>>(cap, cap_len, embed, b_ih, b_hh,
                                       v_wn, g_wn, b_cls, Wc, out);
}